// Round 2
// baseline (3280.462 us; speedup 1.0000x reference)
//
#include <hip/hip_runtime.h>
#include <stdint.h>

#define B_   128
#define T_   128
#define D_   2048
#define H_   512
#define G3   1536
#define CH   1024
#define KC   512
#define OUTD 2048
#define IND  5120
#define TP   168
#define MPAD 160
#define NWG  64
#define SROW 520

typedef short vb8 __attribute__((ext_vector_type(8)));
typedef float v4f __attribute__((ext_vector_type(4)));

__device__ __forceinline__ unsigned short f2b(float f) {
  unsigned u = __float_as_uint(f);
  u = (u + 0x7FFFu + ((u >> 16) & 1u)) >> 16;
  return (unsigned short)u;
}
__device__ __forceinline__ float b2f(unsigned short u) {
  return __uint_as_float((unsigned)u << 16);
}
__device__ __forceinline__ vb8 cvt8(const float* p) {
  float4 a = *reinterpret_cast<const float4*>(p);
  float4 b = *reinterpret_cast<const float4*>(p + 4);
  vb8 r;
  r[0] = (short)f2b(a.x); r[1] = (short)f2b(a.y);
  r[2] = (short)f2b(a.z); r[3] = (short)f2b(a.w);
  r[4] = (short)f2b(b.x); r[5] = (short)f2b(b.y);
  r[6] = (short)f2b(b.z); r[7] = (short)f2b(b.w);
  return r;
}

// ---------------- fc_w [5120][2048] f32 -> [2048][5120] bf16 ----------------
__global__ void k_tcvt(const float* __restrict__ in, unsigned short* __restrict__ out) {
  __shared__ float tile[32][33];
  const int tx = threadIdx.x & 31;
  const int ty = threadIdx.x >> 5; // 0..7
  const int n0 = blockIdx.x * 32;
  const int k0 = blockIdx.y * 32;
#pragma unroll
  for (int i = 0; i < 4; ++i)
    tile[ty + 8 * i][tx] = in[(size_t)(k0 + ty + 8 * i) * OUTD + n0 + tx];
  __syncthreads();
#pragma unroll
  for (int i = 0; i < 4; ++i)
    out[(size_t)(n0 + ty + 8 * i) * IND + k0 + tx] = f2b(tile[tx][ty + 8 * i]);
}

// ---------------- shared bf16 MFMA GEMM ----------------
// C[m][n] = sum_k A[m][k] * Bm[n][k]  (+bias[n])
// AF/BF: source dtype 1=f32 (convert during staging), 0=bf16.
// EPI==0: store C (CB: 1=bf16, 0=f32). EPI==1: conv epilogue (relu+max over tau, atomicMax).
template<int EPI, int AF, int BF, int CB>
__global__ __launch_bounds__(256) void k_gemm(
    const void* __restrict__ Av,
    const void* __restrict__ Bv,
    const float* __restrict__ bias,
    void* __restrict__ Cv,
    int K, int lda, int ldc, int convw)
{
  __shared__ unsigned short sA[128 * 40];
  __shared__ unsigned short sB[128 * 40];
  const unsigned short* A16 = (const unsigned short*)Av;
  const float*          A32 = (const float*)Av;
  const unsigned short* B16 = (const unsigned short*)Bv;
  const float*          B32 = (const float*)Bv;
  float*          C32 = (float*)Cv;
  unsigned short* C16 = (unsigned short*)Cv;

  const int tid  = threadIdx.x;
  const int lane = tid & 63;
  const int wv   = tid >> 6;
  const int wr   = wv >> 1;
  const int wc   = wv & 1;
  const int m0   = blockIdx.x * 128;
  const int n0   = blockIdx.y * 128;

  long agoff[2], bgoff[2];
  int  loff[2];
#pragma unroll
  for (int h = 0; h < 2; ++h) {
    int c   = tid + h * 256;
    int row = c >> 2;
    int kg  = (c & 3) * 8;
    long abase;
    if (EPI == 1) {
      int m   = m0 + row;
      int b   = m / MPAD;
      int tau = m - b * MPAD;
      abase = (long)(b * TP + 4 + tau - (convw - 1)) * CH;
    } else {
      abase = (long)(m0 + row) * lda;
    }
    agoff[h] = abase + kg;
    bgoff[h] = (long)(n0 + row) * K + kg;
    loff[h]  = row * 40 + kg;
  }

  v4f acc[4][4] = {};
  const int kq = (lane >> 4) * 8;
  const int fr = lane & 15;

  for (int k0 = 0; k0 < K; k0 += 32) {
    vb8 ra[2], rb[2];
#pragma unroll
    for (int h = 0; h < 2; ++h) {
      if (AF) ra[h] = cvt8(A32 + agoff[h] + k0);
      else    ra[h] = *reinterpret_cast<const vb8*>(A16 + agoff[h] + k0);
      if (BF) rb[h] = cvt8(B32 + bgoff[h] + k0);
      else    rb[h] = *reinterpret_cast<const vb8*>(B16 + bgoff[h] + k0);
    }
    __syncthreads();
#pragma unroll
    for (int h = 0; h < 2; ++h) {
      *reinterpret_cast<vb8*>(sA + loff[h]) = ra[h];
      *reinterpret_cast<vb8*>(sB + loff[h]) = rb[h];
    }
    __syncthreads();
    vb8 af[4], bfr[4];
#pragma unroll
    for (int i = 0; i < 4; ++i) {
      af[i]  = *reinterpret_cast<const vb8*>(sA + (wr * 64 + i * 16 + fr) * 40 + kq);
      bfr[i] = *reinterpret_cast<const vb8*>(sB + (wc * 64 + i * 16 + fr) * 40 + kq);
    }
#pragma unroll
    for (int i = 0; i < 4; ++i)
#pragma unroll
      for (int j = 0; j < 4; ++j)
        acc[i][j] = __builtin_amdgcn_mfma_f32_16x16x32_bf16(af[i], bfr[j], acc[i][j], 0, 0, 0);
  }

  const int rl = lane >> 4;
#pragma unroll
  for (int i = 0; i < 4; ++i) {
#pragma unroll
    for (int j = 0; j < 4; ++j) {
      int col = n0 + wc * 64 + j * 16 + fr;
      float bs = bias[col];
      if (EPI == 0) {
#pragma unroll
        for (int r = 0; r < 4; ++r) {
          int m = m0 + wr * 64 + i * 16 + rl * 4 + r;
          float v = acc[i][j][r] + bs;
          if (CB) C16[(long)m * ldc + col] = f2b(v);
          else    C32[(long)m * ldc + col] = v;
        }
      } else {
        int mf = m0 + wr * 64 + i * 16;     // frag first row; 16 | 160 so single b per frag
        int b  = mf / MPAD;
        int tf = mf - b * MPAD;
        float mx = 0.f;
#pragma unroll
        for (int r = 0; r < 4; ++r) {
          int tau = tf + rl * 4 + r;
          float v = acc[i][j][r] + bs;
          v = v > 0.f ? v : 0.f;
          if (tau < T_ + convw - 1) mx = v > mx ? v : mx;
        }
        mx = fmaxf(mx, __shfl_xor(mx, 16));
        mx = fmaxf(mx, __shfl_xor(mx, 32));
        if (rl == 0 && tf < T_ + convw - 1)
          atomicMax(reinterpret_cast<int*>(C32 + (long)b * ldc + col), __float_as_int(mx));
      }
    }
  }
}

// ---------------- persistent bidirectional GRU scan ----------------
// 64 WGs: 32 per direction, each owns 16 hidden units (w_hh slice in LDS, 49.9KB).
// h exchanged via global double-buffered bf16; fenced counter barrier per step.
__global__ __launch_bounds__(256) void k_scan(
    const float* __restrict__ whhf, const float* __restrict__ whhb,
    const float* __restrict__ bhhf, const float* __restrict__ bhhb,
    const unsigned short* __restrict__ xw,
    const int* __restrict__ lengths,
    unsigned short* __restrict__ hbuf,
    unsigned short* __restrict__ xpad,
    float* __restrict__ meang,
    unsigned int* __restrict__ cnt)
{
  __shared__ unsigned short sw[48 * SROW];
  const int wg  = blockIdx.x;
  const int dir = wg >> 5;
  const int c0  = (wg & 31) * 16;
  const int tid = threadIdx.x;
  const int lane = tid & 63;
  const int wv  = tid >> 6;
  const float* whh = dir ? whhb : whhf;
  const float* bhh = dir ? bhhb : bhhf;
  const unsigned short* xwd = xw + (size_t)dir * ((size_t)B_ * T_ * G3);
  unsigned short* hb = hbuf + dir * (2 * B_ * H_);

  for (int q = 0; q < 48; ++q) {
    int sr = (q >> 4) * H_ + c0 + (q & 15);
    for (int e = tid; e < H_; e += 256)
      sw[q * SROW + e] = f2b(whh[(size_t)sr * H_ + e]);
  }
  __syncthreads();

  const int fr = lane & 15;
  const int kq = (lane >> 4) * 8;
  const int rl = lane >> 4;
  const int u  = c0 + fr;

  int myb[8]; int mylen[8];
  float hst[8]; float macc[8];
#pragma unroll
  for (int mt = 0; mt < 2; ++mt)
#pragma unroll
    for (int j = 0; j < 4; ++j) {
      int b = wv * 32 + mt * 16 + rl * 4 + j;
      myb[mt * 4 + j] = b;
      mylen[mt * 4 + j] = lengths[b];
      hst[mt * 4 + j] = 0.f;
      macc[mt * 4 + j] = 0.f;
    }

  const float bh0 = bhh[u];
  const float bh1 = bhh[H_ + u];
  const float bh2 = bhh[2 * H_ + u];

  for (int s = 0; s < T_; ++s) {
    const int t = dir ? (T_ - 1 - s) : s;
    v4f acc[2][3] = {};

    if (s > 0) {
      const unsigned short* hp = hb + ((s - 1) & 1) * (B_ * H_);
#pragma unroll 4
      for (int ks = 0; ks < 16; ++ks) {
        vb8 a[2], bb[3];
#pragma unroll
        for (int mt = 0; mt < 2; ++mt)
          a[mt] = *reinterpret_cast<const vb8*>(hp + (wv * 32 + mt * 16 + fr) * H_ + ks * 32 + kq);
#pragma unroll
        for (int g = 0; g < 3; ++g)
          bb[g] = *reinterpret_cast<const vb8*>(sw + (g * 16 + fr) * SROW + ks * 32 + kq);
#pragma unroll
        for (int mt = 0; mt < 2; ++mt)
#pragma unroll
          for (int g = 0; g < 3; ++g)
            acc[mt][g] = __builtin_amdgcn_mfma_f32_16x16x32_bf16(a[mt], bb[g], acc[mt][g], 0, 0, 0);
      }
    }

    unsigned short* hc = hb + (s & 1) * (B_ * H_);
#pragma unroll
    for (int mt = 0; mt < 2; ++mt)
#pragma unroll
      for (int j = 0; j < 4; ++j) {
        const int idx = mt * 4 + j;
        const int b   = myb[idx];
        const unsigned short* xp = xwd + ((size_t)b * T_ + t) * G3 + u;
        float xr = b2f(xp[0]), xz = b2f(xp[H_]), xn = b2f(xp[2 * H_]);
        float hr = acc[mt][0][j] + bh0;
        float hz = acc[mt][1][j] + bh1;
        float hn = acc[mt][2][j] + bh2;
        float r = 1.f / (1.f + __expf(-(xr + hr)));
        float z = 1.f / (1.f + __expf(-(xz + hz)));
        float ax = xn + r * hn;
        float n = 2.f / (1.f + __expf(-2.f * ax)) - 1.f;
        float h = (1.f - z) * n + z * hst[idx];
        hst[idx] = h;
        hc[b * H_ + u] = f2b(h);
        if (t < mylen[idx]) {
          xpad[((size_t)b * TP + 4 + t) * CH + dir * H_ + u] = f2b(h);
          macc[idx] += h;
        }
      }

    if (s < T_ - 1) {
      __syncthreads();                 // all waves' h-stores drained to L2
      if (tid == 0) {
        __threadfence();               // agent fence: write back this XCD's L2
        __hip_atomic_fetch_add(cnt, 1u, __ATOMIC_RELEASE, __HIP_MEMORY_SCOPE_AGENT);
        const unsigned tgt = (unsigned)(s + 1) * NWG;
        while (__hip_atomic_load(cnt, __ATOMIC_ACQUIRE, __HIP_MEMORY_SCOPE_AGENT) < tgt)
          __builtin_amdgcn_s_sleep(1);
        __threadfence();               // invalidate L1/L2 before the WG's h-reads
      }
      __syncthreads();
    }
  }

#pragma unroll
  for (int mt = 0; mt < 2; ++mt)
#pragma unroll
    for (int j = 0; j < 4; ++j) {
      const int idx = mt * 4 + j;
      meang[myb[idx] * CH + dir * H_ + u] = macc[idx] / (float)mylen[idx];
    }
}

// ---------------- feats assembly [128][5120] bf16 ----------------
__global__ void k_feats(const float* __restrict__ mg, const float* __restrict__ co,
                        const float* __restrict__ vo, unsigned short* __restrict__ out) {
  int i = blockIdx.x * 256 + threadIdx.x;
  int b = i / IND, c = i - b * IND;
  float v;
  if (c < CH) v = mg[b * CH + c];
  else if (c < CH + OUTD) v = co[b * OUTD + (c - CH)];
  else v = vo[b * D_ + (c - CH - OUTD)];
  out[i] = f2b(v);
}

// ---------------- BN + L2 normalize ----------------
__global__ __launch_bounds__(256) void k_bnnorm(const float* __restrict__ x,
    const float* __restrict__ g, const float* __restrict__ bt,
    const float* __restrict__ mn, const float* __restrict__ vr,
    float* __restrict__ out) {
  const int b = blockIdx.x;
  __shared__ float red[4];
  float vals[8];
  float ss = 0.f;
#pragma unroll
  for (int i = 0; i < 8; ++i) {
    int c = threadIdx.x + i * 256;
    float y = g[c] * (x[(size_t)b * OUTD + c] - mn[c]) / sqrtf(vr[c] + 1e-5f) + bt[c];
    vals[i] = y;
    ss += y * y;
  }
#pragma unroll
  for (int s2 = 1; s2 < 64; s2 <<= 1) ss += __shfl_xor(ss, s2);
  if ((threadIdx.x & 63) == 0) red[threadIdx.x >> 6] = ss;
  __syncthreads();
  float inv = 1.f / sqrtf(red[0] + red[1] + red[2] + red[3]);
#pragma unroll
  for (int i = 0; i < 8; ++i)
    out[(size_t)b * OUTD + threadIdx.x + i * 256] = vals[i] * inv;
}

extern "C" void kernel_launch(void* const* d_in, const int* in_sizes, int n_in,
                              void* d_out, int out_size, void* d_ws, size_t ws_size,
                              hipStream_t stream) {
  (void)in_sizes; (void)n_in; (void)out_size; (void)ws_size;
  const float* videos = (const float*)d_in[0];
  const float* vorig  = (const float*)d_in[1];
  const int*   lens   = (const int*)d_in[2];
  const float* wihf = (const float*)d_in[4];
  const float* whhf = (const float*)d_in[5];
  const float* bihf = (const float*)d_in[6];
  const float* bhhf = (const float*)d_in[7];
  const float* wihb = (const float*)d_in[8];
  const float* whhb = (const float*)d_in[9];
  const float* bihb = (const float*)d_in[10];
  const float* bhhb = (const float*)d_in[11];
  const float* cw[4] = {(const float*)d_in[12], (const float*)d_in[14],
                        (const float*)d_in[16], (const float*)d_in[18]};
  const float* cb[4] = {(const float*)d_in[13], (const float*)d_in[15],
                        (const float*)d_in[17], (const float*)d_in[19]};
  const float* fcw = (const float*)d_in[20];
  const float* fcb = (const float*)d_in[21];
  const float* bng = (const float*)d_in[22];
  const float* bnb = (const float*)d_in[23];
  const float* bnm = (const float*)d_in[24];
  const float* bnv = (const float*)d_in[25];
  float* out = (float*)d_out;

  char* ws = (char*)d_ws;
  size_t off = 0;
  auto alloc = [&](size_t bytes) -> void* {
    void* p = ws + off;
    off = (off + bytes + 255) & ~(size_t)255;
    return p;
  };
  unsigned int*   cnt    = (unsigned int*)alloc(1024);
  unsigned short* xw16   = (unsigned short*)alloc((size_t)2 * B_ * T_ * G3 * 2);
  unsigned short* hbuf   = (unsigned short*)alloc((size_t)2 * 2 * B_ * H_ * 2);
  unsigned short* xpad   = (unsigned short*)alloc((size_t)B_ * TP * CH * 2);
  float*          meang  = (float*)alloc((size_t)B_ * CH * 4);
  float*          conout = (float*)alloc((size_t)B_ * OUTD * 4);
  unsigned short* fcT    = (unsigned short*)alloc((size_t)OUTD * IND * 2);
  unsigned short* feats  = (unsigned short*)alloc((size_t)B_ * IND * 2);
  float*          fcout  = (float*)alloc((size_t)B_ * OUTD * 4);
  // total ws usage ~170 MB

  hipMemsetAsync(cnt, 0, 1024, stream);
  hipMemsetAsync(xpad, 0, (size_t)B_ * TP * CH * 2, stream);
  hipMemsetAsync(conout, 0, (size_t)B_ * OUTD * 4, stream);

  k_tcvt<<<dim3(64, 160), 256, 0, stream>>>(fcw, fcT);

  // xw = videos @ w_ih^T + b_ih (both directions), f32 sources, bf16 out
  k_gemm<0, 1, 1, 1><<<dim3(128, 12), 256, 0, stream>>>(videos, wihf, bihf, xw16, D_, D_, G3, 0);
  k_gemm<0, 1, 1, 1><<<dim3(128, 12), 256, 0, stream>>>(videos, wihb, bihb,
                                                        xw16 + (size_t)B_ * T_ * G3, D_, D_, G3, 0);

  // recurrent scan (normal launch; 64 blocks trivially co-resident on 256 CUs)
  k_scan<<<dim3(NWG), dim3(256), 0, stream>>>(whhf, whhb, bhhf, bhhb, xw16, lens,
                                              hbuf, xpad, meang, cnt);

  // convs (as GEMM over padded time) with fused relu+bias+time-max; B = f32 conv_w
  for (int i = 0; i < 4; ++i) {
    int w = i + 2;
    k_gemm<1, 0, 1, 0><<<dim3(160, 4), 256, 0, stream>>>(xpad, cw[i], cb[i],
                                                         conout + i * KC, w * CH, 0, OUTD, w);
  }

  k_feats<<<2560, 256, 0, stream>>>(meang, conout, vorig, feats);
  k_gemm<0, 0, 0, 0><<<dim3(1, 16), 256, 0, stream>>>(feats, fcT, fcb, fcout, IND, IND, OUTD, 0);
  k_bnnorm<<<B_, 256, 0, stream>>>(fcout, bng, bnb, bnm, bnv, out);
}

// Round 3
// 2488.030 us; speedup vs baseline: 1.3185x; 1.3185x over previous
//
#include <hip/hip_runtime.h>
#include <stdint.h>

#define B_   128
#define T_   128
#define D_   2048
#define H_   512
#define G3   1536
#define CH   1024
#define KC   512
#define OUTD 2048
#define IND  5120
#define TP   168
#define MPAD 160
#define SROW 520

typedef short vb8 __attribute__((ext_vector_type(8)));
typedef float v4f __attribute__((ext_vector_type(4)));

__device__ __forceinline__ unsigned short f2b(float f) {
  unsigned u = __float_as_uint(f);
  u = (u + 0x7FFFu + ((u >> 16) & 1u)) >> 16;
  return (unsigned short)u;
}
__device__ __forceinline__ float b2f(unsigned short u) {
  return __uint_as_float((unsigned)u << 16);
}

__device__ __forceinline__ void gl16(const unsigned short* g, unsigned short* l) {
  __builtin_amdgcn_global_load_lds(
      (const __attribute__((address_space(1))) void*)g,
      (__attribute__((address_space(3))) void*)l, 16, 0, 0);
}

// ---------------- f32 -> bf16 elementwise ----------------
__global__ void k_cvt(const float* __restrict__ in, unsigned short* __restrict__ out, int n4) {
  int stride = gridDim.x * blockDim.x;
  for (int i = blockIdx.x * blockDim.x + threadIdx.x; i < n4; i += stride) {
    float4 v = reinterpret_cast<const float4*>(in)[i];
    ushort4 o;
    o.x = f2b(v.x); o.y = f2b(v.y); o.z = f2b(v.z); o.w = f2b(v.w);
    reinterpret_cast<ushort4*>(out)[i] = o;
  }
}

// ---------------- fc_w [5120][2048] f32 -> [2048][5120] bf16 ----------------
__global__ void k_tcvt(const float* __restrict__ in, unsigned short* __restrict__ out) {
  __shared__ float tile[32][33];
  const int tx = threadIdx.x & 31;
  const int ty = threadIdx.x >> 5; // 0..7
  const int n0 = blockIdx.x * 32;
  const int k0 = blockIdx.y * 32;
#pragma unroll
  for (int i = 0; i < 4; ++i)
    tile[ty + 8 * i][tx] = in[(size_t)(k0 + ty + 8 * i) * OUTD + n0 + tx];
  __syncthreads();
#pragma unroll
  for (int i = 0; i < 4; ++i)
    out[(size_t)(n0 + ty + 8 * i) * IND + k0 + tx] = f2b(tile[tx][ty + 8 * i]);
}

// ---------------- bf16 MFMA GEMM, global_load_lds staging (m97 recipe) ----------------
// C[m][n] = sum_k A[m][k] * Bm[n][k]  (+bias[n])
// EPI==0: store C (CB: 1=bf16, 0=f32). EPI==1: conv epilogue (relu+max over tau, atomicMax).
template<int EPI, int CB>
__global__ __launch_bounds__(256) void k_gemm(
    const unsigned short* __restrict__ A,
    const unsigned short* __restrict__ Bm,
    const float* __restrict__ bias,
    void* __restrict__ Cv,
    int K, int lda, int ldc, int convw)
{
  __shared__ unsigned short sA[128 * 32];
  __shared__ unsigned short sB[128 * 32];
  float*          C32 = (float*)Cv;
  unsigned short* C16 = (unsigned short*)Cv;

  const int tid  = threadIdx.x;
  const int lane = tid & 63;
  const int wv   = tid >> 6;
  const int wr   = wv >> 1;
  const int wc   = wv & 1;
  const int m0   = blockIdx.x * 128;
  const int n0   = blockIdx.y * 128;

  // staging addresses: wave wv stages chunks {2wv, 2wv+1}; chunk = 16 rows x 64B
  const unsigned short* ag[2];
  const unsigned short* bg[2];
  unsigned short* al[2];
  unsigned short* bl[2];
#pragma unroll
  for (int q = 0; q < 2; ++q) {
    int c  = wv * 2 + q;
    int r  = c * 16 + (lane >> 2);
    int kc = (lane & 3) * 8;
    long abase;
    if (EPI == 1) {
      int m   = m0 + r;
      int b   = m / MPAD;
      int tau = m - b * MPAD;
      abase = (long)(b * TP + 4 + tau - (convw - 1)) * CH;
    } else {
      abase = (long)(m0 + r) * lda;
    }
    ag[q] = A + abase + kc;
    bg[q] = Bm + (long)(n0 + r) * K + kc;
    al[q] = sA + c * 512;
    bl[q] = sB + c * 512;
  }

  v4f acc[4][4] = {};
  const int kq = (lane >> 4) * 8;
  const int fr = lane & 15;

  for (int k0 = 0; k0 < K; k0 += 32) {
    if (k0) __syncthreads();
#pragma unroll
    for (int q = 0; q < 2; ++q) {
      gl16(ag[q] + k0, al[q]);
      gl16(bg[q] + k0, bl[q]);
    }
    __syncthreads();
    vb8 af[4], bfr[4];
#pragma unroll
    for (int i = 0; i < 4; ++i) {
      af[i]  = *reinterpret_cast<const vb8*>(sA + (wr * 64 + i * 16 + fr) * 32 + kq);
      bfr[i] = *reinterpret_cast<const vb8*>(sB + (wc * 64 + i * 16 + fr) * 32 + kq);
    }
#pragma unroll
    for (int i = 0; i < 4; ++i)
#pragma unroll
      for (int j = 0; j < 4; ++j)
        acc[i][j] = __builtin_amdgcn_mfma_f32_16x16x32_bf16(af[i], bfr[j], acc[i][j], 0, 0, 0);
  }

  const int rl = lane >> 4;
#pragma unroll
  for (int i = 0; i < 4; ++i) {
#pragma unroll
    for (int j = 0; j < 4; ++j) {
      int col = n0 + wc * 64 + j * 16 + fr;
      float bs = bias[col];
      if (EPI == 0) {
#pragma unroll
        for (int r = 0; r < 4; ++r) {
          int m = m0 + wr * 64 + i * 16 + rl * 4 + r;
          float v = acc[i][j][r] + bs;
          if (CB) C16[(long)m * ldc + col] = f2b(v);
          else    C32[(long)m * ldc + col] = v;
        }
      } else {
        int mf = m0 + wr * 64 + i * 16;     // frag first row; 16 | 160 so single b per frag
        int b  = mf / MPAD;
        int tf = mf - b * MPAD;
        float mx = 0.f;
#pragma unroll
        for (int r = 0; r < 4; ++r) {
          int tau = tf + rl * 4 + r;
          float v = acc[i][j][r] + bs;
          v = v > 0.f ? v : 0.f;
          if (tau < T_ + convw - 1) mx = v > mx ? v : mx;
        }
        mx = fmaxf(mx, __shfl_xor(mx, 16));
        mx = fmaxf(mx, __shfl_xor(mx, 32));
        if (rl == 0 && tf < T_ + convw - 1)
          atomicMax(reinterpret_cast<int*>(C32 + (long)b * ldc + col), __float_as_int(mx));
      }
    }
  }
}

// ---------------- persistent bidirectional GRU scan ----------------
// 64 WGs: 32 per direction, each owns 16 hidden units (w_hh slice in LDS, ~49.9KB).
// h exchanged via global double-buffered bf16.
// Per-direction counter barrier: release-add, RELAXED polls, one acquire fence.
__global__ __launch_bounds__(256) void k_scan(
    const float* __restrict__ whhf, const float* __restrict__ whhb,
    const float* __restrict__ bhhf, const float* __restrict__ bhhb,
    const unsigned short* __restrict__ xw,
    const int* __restrict__ lengths,
    unsigned short* __restrict__ hbuf,
    unsigned short* __restrict__ xpad,
    float* __restrict__ meang,
    unsigned int* __restrict__ cnt)
{
  __shared__ unsigned short sw[48 * SROW];
  const int wg  = blockIdx.x;
  const int dir = wg >> 5;
  const int c0  = (wg & 31) * 16;
  const int tid = threadIdx.x;
  const int lane = tid & 63;
  const int wv  = tid >> 6;
  const float* whh = dir ? whhb : whhf;
  const float* bhh = dir ? bhhb : bhhf;
  const unsigned short* xwd = xw + (size_t)dir * ((size_t)B_ * T_ * G3);
  unsigned short* hb = hbuf + dir * (2 * B_ * H_);
  unsigned int* mycnt = cnt + dir * 64;   // 256 B apart per direction

  for (int q = 0; q < 48; ++q) {
    int sr = (q >> 4) * H_ + c0 + (q & 15);
    for (int e = tid; e < H_; e += 256)
      sw[q * SROW + e] = f2b(whh[(size_t)sr * H_ + e]);
  }
  __syncthreads();

  const int fr = lane & 15;
  const int kq = (lane >> 4) * 8;
  const int rl = lane >> 4;
  const int u  = c0 + fr;

  int myb[8]; int mylen[8];
  float hst[8]; float macc[8];
#pragma unroll
  for (int mt = 0; mt < 2; ++mt)
#pragma unroll
    for (int j = 0; j < 4; ++j) {
      int b = wv * 32 + mt * 16 + rl * 4 + j;
      myb[mt * 4 + j] = b;
      mylen[mt * 4 + j] = lengths[b];
      hst[mt * 4 + j] = 0.f;
      macc[mt * 4 + j] = 0.f;
    }

  const float bh0 = bhh[u];
  const float bh1 = bhh[H_ + u];
  const float bh2 = bhh[2 * H_ + u];

  // prefetched xw gates for the CURRENT step
  float pxr[8], pxz[8], pxn[8];
  {
    const int t0 = dir ? (T_ - 1) : 0;
#pragma unroll
    for (int idx = 0; idx < 8; ++idx) {
      const unsigned short* xp = xwd + ((size_t)myb[idx] * T_ + t0) * G3 + u;
      pxr[idx] = b2f(xp[0]); pxz[idx] = b2f(xp[H_]); pxn[idx] = b2f(xp[2 * H_]);
    }
  }

  for (int s = 0; s < T_; ++s) {
    const int t = dir ? (T_ - 1 - s) : s;
    v4f acc[2][3] = {};

    if (s > 0) {
      const unsigned short* hp = hb + ((s - 1) & 1) * (B_ * H_);
#pragma unroll 4
      for (int ks = 0; ks < 16; ++ks) {
        vb8 a[2], bb[3];
#pragma unroll
        for (int mt = 0; mt < 2; ++mt)
          a[mt] = *reinterpret_cast<const vb8*>(hp + (wv * 32 + mt * 16 + fr) * H_ + ks * 32 + kq);
#pragma unroll
        for (int g = 0; g < 3; ++g)
          bb[g] = *reinterpret_cast<const vb8*>(sw + (g * 16 + fr) * SROW + ks * 32 + kq);
#pragma unroll
        for (int mt = 0; mt < 2; ++mt)
#pragma unroll
          for (int g = 0; g < 3; ++g)
            acc[mt][g] = __builtin_amdgcn_mfma_f32_16x16x32_bf16(a[mt], bb[g], acc[mt][g], 0, 0, 0);
      }
    }

    unsigned short* hc = hb + (s & 1) * (B_ * H_);
#pragma unroll
    for (int mt = 0; mt < 2; ++mt)
#pragma unroll
      for (int j = 0; j < 4; ++j) {
        const int idx = mt * 4 + j;
        const int b   = myb[idx];
        float hr = acc[mt][0][j] + bh0;
        float hz = acc[mt][1][j] + bh1;
        float hn = acc[mt][2][j] + bh2;
        float r = 1.f / (1.f + __expf(-(pxr[idx] + hr)));
        float z = 1.f / (1.f + __expf(-(pxz[idx] + hz)));
        float ax = pxn[idx] + r * hn;
        float n = 2.f / (1.f + __expf(-2.f * ax)) - 1.f;
        float h = (1.f - z) * n + z * hst[idx];
        hst[idx] = h;
        hc[b * H_ + u] = f2b(h);
        if (t < mylen[idx]) {
          xpad[((size_t)b * TP + 4 + t) * CH + dir * H_ + u] = f2b(h);
          macc[idx] += h;
        }
      }

    if (s < T_ - 1) {
      // prefetch next step's xw into registers (latency hides under the barrier)
      const int tn = dir ? (T_ - 2 - s) : (s + 1);
#pragma unroll
      for (int idx = 0; idx < 8; ++idx) {
        const unsigned short* xp = xwd + ((size_t)myb[idx] * T_ + tn) * G3 + u;
        pxr[idx] = b2f(xp[0]); pxz[idx] = b2f(xp[H_]); pxn[idx] = b2f(xp[2 * H_]);
      }
      __syncthreads();                 // all waves' h-stores accepted by L2
      if (tid == 0) {
        __hip_atomic_fetch_add(mycnt, 1u, __ATOMIC_RELEASE, __HIP_MEMORY_SCOPE_AGENT);
        const unsigned tgt = (unsigned)(s + 1) * 32;
        while (__hip_atomic_load(mycnt, __ATOMIC_RELAXED, __HIP_MEMORY_SCOPE_AGENT) < tgt)
          __builtin_amdgcn_s_sleep(1);
        __builtin_amdgcn_fence(__ATOMIC_ACQUIRE, "agent");  // one L1/L2 invalidate
      }
      __syncthreads();
    }
  }

#pragma unroll
  for (int mt = 0; mt < 2; ++mt)
#pragma unroll
    for (int j = 0; j < 4; ++j) {
      const int idx = mt * 4 + j;
      meang[myb[idx] * CH + dir * H_ + u] = macc[idx] / (float)mylen[idx];
    }
}

// ---------------- feats assembly [128][5120] bf16 ----------------
__global__ void k_feats(const float* __restrict__ mg, const float* __restrict__ co,
                        const float* __restrict__ vo, unsigned short* __restrict__ out) {
  int i = blockIdx.x * 256 + threadIdx.x;
  int b = i / IND, c = i - b * IND;
  float v;
  if (c < CH) v = mg[b * CH + c];
  else if (c < CH + OUTD) v = co[b * OUTD + (c - CH)];
  else v = vo[b * D_ + (c - CH - OUTD)];
  out[i] = f2b(v);
}

// ---------------- BN + L2 normalize ----------------
__global__ __launch_bounds__(256) void k_bnnorm(const float* __restrict__ x,
    const float* __restrict__ g, const float* __restrict__ bt,
    const float* __restrict__ mn, const float* __restrict__ vr,
    float* __restrict__ out) {
  const int b = blockIdx.x;
  __shared__ float red[4];
  float vals[8];
  float ss = 0.f;
#pragma unroll
  for (int i = 0; i < 8; ++i) {
    int c = threadIdx.x + i * 256;
    float y = g[c] * (x[(size_t)b * OUTD + c] - mn[c]) / sqrtf(vr[c] + 1e-5f) + bt[c];
    vals[i] = y;
    ss += y * y;
  }
#pragma unroll
  for (int s2 = 1; s2 < 64; s2 <<= 1) ss += __shfl_xor(ss, s2);
  if ((threadIdx.x & 63) == 0) red[threadIdx.x >> 6] = ss;
  __syncthreads();
  float inv = 1.f / sqrtf(red[0] + red[1] + red[2] + red[3]);
#pragma unroll
  for (int i = 0; i < 8; ++i)
    out[(size_t)b * OUTD + threadIdx.x + i * 256] = vals[i] * inv;
}

extern "C" void kernel_launch(void* const* d_in, const int* in_sizes, int n_in,
                              void* d_out, int out_size, void* d_ws, size_t ws_size,
                              hipStream_t stream) {
  (void)in_sizes; (void)n_in; (void)out_size; (void)ws_size;
  const float* videos = (const float*)d_in[0];
  const float* vorig  = (const float*)d_in[1];
  const int*   lens   = (const int*)d_in[2];
  const float* wihf = (const float*)d_in[4];
  const float* whhf = (const float*)d_in[5];
  const float* bihf = (const float*)d_in[6];
  const float* bhhf = (const float*)d_in[7];
  const float* wihb = (const float*)d_in[8];
  const float* whhb = (const float*)d_in[9];
  const float* bihb = (const float*)d_in[10];
  const float* bhhb = (const float*)d_in[11];
  const float* cw[4] = {(const float*)d_in[12], (const float*)d_in[14],
                        (const float*)d_in[16], (const float*)d_in[18]};
  const float* cb[4] = {(const float*)d_in[13], (const float*)d_in[15],
                        (const float*)d_in[17], (const float*)d_in[19]};
  const float* fcw = (const float*)d_in[20];
  const float* fcb = (const float*)d_in[21];
  const float* bng = (const float*)d_in[22];
  const float* bnb = (const float*)d_in[23];
  const float* bnm = (const float*)d_in[24];
  const float* bnv = (const float*)d_in[25];
  float* out = (float*)d_out;

  char* ws = (char*)d_ws;
  size_t off = 0;
  auto alloc = [&](size_t bytes) -> void* {
    void* p = ws + off;
    off = (off + bytes + 255) & ~(size_t)255;
    return p;
  };
  unsigned int*   cnt    = (unsigned int*)alloc(1024);
  unsigned short* xw16   = (unsigned short*)alloc((size_t)2 * B_ * T_ * G3 * 2);  // 100.7 MB
  unsigned short* hbuf   = (unsigned short*)alloc((size_t)2 * 2 * B_ * H_ * 2);
  float*          meang  = (float*)alloc((size_t)B_ * CH * 4);
  float*          conout = (float*)alloc((size_t)B_ * OUTD * 4);
  unsigned short* feats  = (unsigned short*)alloc((size_t)B_ * IND * 2);
  float*          fcout  = (float*)alloc((size_t)B_ * OUTD * 4);
  unsigned short* wihf16 = (unsigned short*)alloc((size_t)G3 * D_ * 2);
  unsigned short* wihb16 = (unsigned short*)alloc((size_t)G3 * D_ * 2);
  unsigned short* cw16   = (unsigned short*)alloc((size_t)KC * 14 * CH * 2);
  unsigned short* vid16  = (unsigned short*)alloc((size_t)B_ * T_ * D_ * 2);      // 67.1 MB
  // vid16 is dead after the xw GEMMs; xpad (44.0 MB) + fcT (21.0 MB) alias it.
  unsigned short* xpad = vid16;
  unsigned short* fcT  = vid16 + (size_t)B_ * TP * CH;
  // total ws usage ~200 MB

  hipMemsetAsync(cnt, 0, 1024, stream);
  hipMemsetAsync(conout, 0, (size_t)B_ * OUTD * 4, stream);

  // pre-convert all GEMM operands to bf16
  k_cvt<<<2048, 256, 0, stream>>>(videos, vid16, B_ * T_ * D_ / 4);
  k_cvt<<<512, 256, 0, stream>>>(wihf, wihf16, G3 * D_ / 4);
  k_cvt<<<512, 256, 0, stream>>>(wihb, wihb16, G3 * D_ / 4);
  {
    size_t cwoff = 0;
    for (int i = 0; i < 4; ++i) {
      int w = i + 2;
      int n = KC * w * CH;
      k_cvt<<<256, 256, 0, stream>>>(cw[i], cw16 + cwoff, n / 4);
      cwoff += (size_t)n;
    }
  }

  // xw = videos @ w_ih^T + b_ih (both directions), bf16 out
  k_gemm<0, 1><<<dim3(128, 12), 256, 0, stream>>>(vid16, wihf16, bihf, xw16, D_, D_, G3, 0);
  k_gemm<0, 1><<<dim3(128, 12), 256, 0, stream>>>(vid16, wihb16, bihb,
                                                  xw16 + (size_t)B_ * T_ * G3, D_, D_, G3, 0);

  // vid16 now dead: init aliased xpad + fcT
  hipMemsetAsync(xpad, 0, (size_t)B_ * TP * CH * 2, stream);
  k_tcvt<<<dim3(64, 160), 256, 0, stream>>>(fcw, fcT);

  // recurrent scan (64 blocks trivially co-resident on 256 CUs)
  k_scan<<<dim3(64), dim3(256), 0, stream>>>(whhf, whhb, bhhf, bhhb, xw16, lens,
                                             hbuf, xpad, meang, cnt);

  // convs (as GEMM over padded time) with fused relu+bias+time-max
  {
    size_t cwoff = 0;
    for (int i = 0; i < 4; ++i) {
      int w = i + 2;
      k_gemm<1, 0><<<dim3(160, 4), 256, 0, stream>>>(xpad, cw16 + cwoff, cb[i],
                                                     conout + i * KC, w * CH, 0, OUTD, w);
      cwoff += (size_t)KC * w * CH;
    }
  }

  k_feats<<<2560, 256, 0, stream>>>(meang, conout, vorig, feats);
  k_gemm<0, 0><<<dim3(1, 16), 256, 0, stream>>>(feats, fcT, fcb, fcout, IND, IND, OUTD, 0);
  k_bnnorm<<<B_, 256, 0, stream>>>(fcout, bng, bnb, bnm, bnv, out);
}